// Round 11
// baseline (303.503 us; speedup 1.0000x reference)
//
#include <hip/hip_runtime.h>
#include <stdint.h>

#define NA 9
#define HH 50
#define WW 50
#define NPROP (HH*WW*NA)      // 22500
#define PRE_NMS 4000
#define POST_NMS 300
#define NWORDS 63             // windows / suppression words per row
#define MROWS 4032            // padded rows per image (63 * 64)
#define SELN 8192             // compaction capacity
#define NMS_T 0.7f
#define FSTRIDE 16.0f

typedef unsigned long long ull;

__device__ __forceinline__ uint32_t f32_ord(float s) {
    uint32_t u = __float_as_uint(s);
    return (u & 0x80000000u) ? ~u : (u | 0x80000000u);
}

// ---------------------------------------------------------------------------
// Kernel 1: fused decode + 12-bit LDS histogram + threshold + compaction.
// One 1024-thread block per image. Pass 1 decodes boxes (global) and builds
// a 4096-bucket LDS histogram of the score-order prefix. Threshold bucket via
// suffix scan. Pass 2 re-reads scores only, compacts keys >= thr to ckeys.
// ---------------------------------------------------------------------------
__global__ __launch_bounds__(1024) void decode_compact(
        const float* __restrict__ scores,
        const float* __restrict__ deltas,
        const float* __restrict__ im_info,
        const float* __restrict__ anchors,
        float4* __restrict__ boxes4,
        ull* __restrict__ ckeys,
        int* __restrict__ mcount) {
    __shared__ int hist[4096];
    __shared__ int sA[1024], sB[1024];
    __shared__ int sSeg, aboveC, thr, lcount;
    int img = blockIdx.x, tid = threadIdx.x;
    for (int e = tid; e < 4096; e += 1024) hist[e] = 0;
    float wmax = im_info[img*3+1] - 1.0f;
    float hmax = im_info[img*3+0] - 1.0f;
    __syncthreads();

    // --- pass 1: decode + histogram ---
    for (int i = tid; i < NPROP; i += 1024) {
        int a   = i % NA;
        int pos = i / NA;
        int w   = pos % WW;
        int h   = pos / WW;

        float score = scores[((size_t)img*2*NA + NA + a)*(HH*WW) + pos];
        atomicAdd(&hist[f32_ord(score) >> 20], 1);

        float ax1 = anchors[a*4+0], ay1 = anchors[a*4+1];
        float ax2 = anchors[a*4+2], ay2 = anchors[a*4+3];
        float sx = (float)w * FSTRIDE, sy = (float)h * FSTRIDE;
        float x1 = ax1 + sx, y1 = ay1 + sy, x2 = ax2 + sx, y2 = ay2 + sy;
        float bw = x2 - x1 + 1.0f;
        float bh = y2 - y1 + 1.0f;
        float cx = x1 + 0.5f * bw;
        float cy = y1 + 0.5f * bh;

        const float* dp = deltas + (size_t)img*4*NA*(HH*WW);
        float dx = dp[(4*a+0)*(HH*WW)+pos];
        float dy = dp[(4*a+1)*(HH*WW)+pos];
        float dw = dp[(4*a+2)*(HH*WW)+pos];
        float dh = dp[(4*a+3)*(HH*WW)+pos];

        float pcx = dx * bw + cx;
        float pcy = dy * bh + cy;
        float pw  = expf(dw) * bw;
        float ph  = expf(dh) * bh;

        float px1 = fminf(fmaxf(pcx - 0.5f*pw, 0.0f), wmax);
        float py1 = fminf(fmaxf(pcy - 0.5f*ph, 0.0f), hmax);
        float px2 = fminf(fmaxf(pcx + 0.5f*pw, 0.0f), wmax);
        float py2 = fminf(fmaxf(pcy + 0.5f*ph, 0.0f), hmax);

        boxes4[(size_t)img*NPROP + i] = make_float4(px1, py1, px2, py2);
    }
    __syncthreads();

    // --- threshold: coarse 4-sums, suffix scan, fine search over 4 ---
    {
        int t4 = tid << 2;
        sA[tid] = hist[t4] + hist[t4+1] + hist[t4+2] + hist[t4+3];
    }
    __syncthreads();
    int* curp = sA; int* nxtp = sB;
    for (int d = 1; d < 1024; d <<= 1) {
        int v = curp[tid] + ((tid + d < 1024) ? curp[tid + d] : 0);
        nxtp[tid] = v;
        __syncthreads();
        int* tmp = curp; curp = nxtp; nxtp = tmp;
    }
    {
        int c0 = curp[tid];
        int c1 = (tid < 1023) ? curp[tid + 1] : 0;
        if (c0 >= PRE_NMS && c1 < PRE_NMS) { sSeg = tid; aboveC = c1; }
    }
    __syncthreads();
    if (tid == 0) {
        int cum = aboveC, t = sSeg << 2;
        for (int w = 3; w >= 0; --w) {
            int nc = cum + hist[(sSeg << 2) + w];
            if (nc >= PRE_NMS) { t = (sSeg << 2) + w; break; }
            cum = nc;
        }
        thr = t; lcount = 0;
    }
    __syncthreads();

    // --- pass 2: compact keys >= thr ---
    ull* ck = ckeys + (size_t)img * SELN;
    {
        int th = thr;
        for (int i = tid; i < NPROP; i += 1024) {
            int a = i % NA, pos = i / NA;
            float score = scores[((size_t)img*2*NA + NA + a)*(HH*WW) + pos];
            uint32_t so = f32_ord(score);
            if ((int)(so >> 20) >= th) {
                int p = atomicAdd(&lcount, 1);
                if (p < SELN) ck[p] = ((ull)so << 32) | (ull)(0xFFFFFFFFu - (uint32_t)i);
            }
        }
    }
    __syncthreads();
    int M = lcount; if (M > SELN) M = SELN;
    if (tid == 0) mcount[img] = M;
    for (int e = M + tid; e < SELN; e += 1024) ck[e] = 0ull;
}

// ---------------------------------------------------------------------------
// Kernel 2: rank-by-count scatter (keys unique => rank is exact permutation).
// ---------------------------------------------------------------------------
__global__ __launch_bounds__(256) void rank_scatter(
        const ull* __restrict__ ckeys,
        const int* __restrict__ mcount,
        const float4* __restrict__ boxes4,
        float4* __restrict__ gboxes) {
    __shared__ ull lk[SELN];
    __shared__ int sM;
    int img = blockIdx.y, rb = blockIdx.x, tid = threadIdx.x;
    if (tid == 0) sM = mcount[img];
    __syncthreads();
    int M = sM;
    if (rb * 256 >= M) return;
    int Ms = (M + 255) & ~255;

    const ull* kb = ckeys + (size_t)img * SELN;
    for (int e = tid; e < Ms; e += 256) lk[e] = (e < M) ? kb[e] : 0ull;
    __syncthreads();

    int row = rb * 256 + tid;
    if (row >= M) return;
    ull my = lk[row];

    int rank = 0;
    #pragma unroll 8
    for (int e = 0; e < Ms; ++e) rank += (lk[e] > my) ? 1 : 0;

    if (rank < PRE_NMS) {
        uint32_t idx = 0xFFFFFFFFu - (uint32_t)(my & 0xFFFFFFFFull);
        gboxes[(size_t)img*PRE_NMS + rank] = boxes4[(size_t)img*NPROP + idx];
    }
}

// ---------------------------------------------------------------------------
// Kernel 3: suppression bit-matrix + compact transposed diag/superdiag.
//  - mask row-major words for cb>rb (bit k = row i suppresses col cb*64+k)
//  - diag slot + diagT: transposed (bit k = row k suppresses col tid)
//  - superT (cb==rb+1): transposed (bit k = row rb*64+k suppresses col tid)
// ---------------------------------------------------------------------------
__global__ __launch_bounds__(64) void mask_kernel(const float4* __restrict__ gboxes,
                                                  ull* __restrict__ mask,
                                                  ull* __restrict__ diagT,
                                                  ull* __restrict__ superT) {
    int rb = blockIdx.x, cb = blockIdx.y, b = blockIdx.z;
    if (cb < rb) return;
    __shared__ float cx1[64], cy1[64], cx2[64], cy2[64], car[64];
    __shared__ float rx1[64], ry1[64], rx2[64], ry2[64], rar[64];
    int tid = threadIdx.x;

    int j0 = cb*64 + tid;
    float4 cbx = (j0 < PRE_NMS) ? gboxes[(size_t)b*PRE_NMS + j0]
                                : make_float4(0.f,0.f,0.f,0.f);
    cx1[tid]=cbx.x; cy1[tid]=cbx.y; cx2[tid]=cbx.z; cy2[tid]=cbx.w;
    car[tid]=(cbx.z-cbx.x+1.0f)*(cbx.w-cbx.y+1.0f);

    int i = rb*64 + tid;
    float4 rbx = (i < PRE_NMS) ? gboxes[(size_t)b*PRE_NMS + i]
                               : make_float4(0.f,0.f,0.f,0.f);
    rx1[tid]=rbx.x; ry1[tid]=rbx.y; rx2[tid]=rbx.z; ry2[tid]=rbx.w;
    rar[tid]=(rbx.z-rbx.x+1.0f)*(rbx.w-rbx.y+1.0f);
    __syncthreads();

    // superdiagonal transposed block: my column box vs staged rows
    if (cb == rb + 1) {
        float mx1=cbx.x, my1=cbx.y, mx2=cbx.z, my2=cbx.w, marea=car[tid];
        ull tb = 0;
        #pragma unroll 16
        for (int k = 0; k < 64; ++k) {
            float xx1 = fmaxf(mx1, rx1[k]);
            float yy1 = fmaxf(my1, ry1[k]);
            float xx2 = fminf(mx2, rx2[k]);
            float yy2 = fminf(my2, ry2[k]);
            float ww = fmaxf(xx2 - xx1 + 1.0f, 0.0f);
            float hh = fmaxf(yy2 - yy1 + 1.0f, 0.0f);
            float inter = ww * hh;
            float iou = inter / (marea + rar[k] - inter);
            if (iou > NMS_T) tb |= (1ull << k);
        }
        superT[((size_t)b*(NWORDS-1) + rb)*64 + tid] = tb;
    }

    const bool diag = (rb == cb);
    if (i >= PRE_NMS) {
        if (diag) diagT[((size_t)b*NWORDS + rb)*64 + tid] = 0ull;
        return;
    }
    float ix1=rbx.x, iy1=rbx.y, ix2=rbx.z, iy2=rbx.w, iarea=rar[tid];

    ull bits = 0;
    #pragma unroll 16
    for (int k = 0; k < 64; ++k) {
        float xx1 = fmaxf(ix1, cx1[k]);
        float yy1 = fmaxf(iy1, cy1[k]);
        float xx2 = fminf(ix2, cx2[k]);
        float yy2 = fminf(iy2, cy2[k]);
        float ww = fmaxf(xx2 - xx1 + 1.0f, 0.0f);
        float hh = fmaxf(yy2 - yy1 + 1.0f, 0.0f);
        float inter = ww * hh;
        float iou = inter / (iarea + car[k] - inter);
        bool cond = diag ? (tid > k) : ((cb*64 + k) < PRE_NMS);
        if (cond & (iou > NMS_T)) bits |= (1ull << k);
    }
    mask[(((size_t)b*MROWS + i) << 6) + cb] = bits;
    if (diag) diagT[((size_t)b*NWORDS + rb)*64 + tid] = bits;
}

// ---------------------------------------------------------------------------
// Kernel 4: greedy scan v6. diagT/superT burst-loaded to LDS once. Per
// window: within-window via diag ballot; next window via superT ballot
// (registers only); windows >= wi+2 via batched independent row loads with a
// full window of latency slack (folded into supp at the next boundary).
// ---------------------------------------------------------------------------
__global__ __launch_bounds__(64) void scan_kernel(const ull* __restrict__ mask,
                                                  const ull* __restrict__ diagT,
                                                  const ull* __restrict__ superT,
                                                  const float4* __restrict__ gboxes,
                                                  float* __restrict__ out) {
    __shared__ __align__(16) ull dTl[NWORDS*64];
    __shared__ __align__(16) ull sTl[(NWORDS-1)*64];
    __shared__ int keep_idx[POST_NMS];
    int b = blockIdx.x;
    int lane = threadIdx.x;

    // burst-load transposed tables (coalesced 16B loads)
    {
        const ulonglong2* gd = (const ulonglong2*)(diagT + (size_t)b*NWORDS*64);
        ulonglong2* dd = (ulonglong2*)dTl;
        for (int e = lane; e < NWORDS*32; e += 64) dd[e] = gd[e];
        const ulonglong2* gs = (const ulonglong2*)(superT + (size_t)b*(NWORDS-1)*64);
        ulonglong2* ds = (ulonglong2*)sTl;
        for (int e = lane; e < (NWORDS-1)*32; e += 64) ds[e] = gs[e];
    }
    __syncthreads();

    const ull* mrow = mask + ((size_t)b * MROWS << 6);
    ull supp = 0;
    if (lane == NWORDS-1) supp = 0xFFFFFFFF00000000ull;  // candidates >= 4000
    if (lane >= NWORDS)   supp = ~0ull;
    int kept = 0;
    bool done = false;
    ull corr = 0;   // next-window correction (uniform)
    ull pend = 0;   // row loads issued last window

    ull tw = dTl[lane];   // window 0 transposed diag word
    for (int wi = 0; wi < NWORDS && !done; ++wi) {
        ull twn = (wi + 1 < NWORDS) ? dTl[(wi+1)*64 + lane] : 0ull;
        ull tw2 = (wi + 1 < NWORDS) ? sTl[wi*64 + lane]     : 0ull;

        ull cur = __shfl(supp, wi) | corr;
        supp |= pend; pend = 0;          // fold last window's loads (slack >= 1 window)
        ull avail = ~cur;
        ull keptmask = 0;

        while (avail) {
            int c = __builtin_ctzll(avail);
            if (lane == 0) keep_idx[kept] = (wi << 6) + c;
            ++kept;
            keptmask |= (1ull << c);
            if (kept >= POST_NMS) { done = true; break; }
            ull roww = __ballot((int)((tw >> c) & 1ull));
            avail &= ~roww;
            avail &= avail - 1;
        }

        if (!done) {
            corr = __ballot((int)((tw2 & keptmask) != 0ull));
            // batched independent loads of kept rows' future words
            const bool ld = (lane > wi) && (lane < NWORDS);
            const ull* base = mrow + ((size_t)wi << 12) + lane;
            ull km = keptmask;
            while (km) {
                int c0 = __builtin_ctzll(km); km &= km - 1;
                int c1 = -1, c2 = -1, c3 = -1, c4 = -1, c5 = -1, c6 = -1, c7 = -1;
                if (km) { c1 = __builtin_ctzll(km); km &= km - 1; }
                if (km) { c2 = __builtin_ctzll(km); km &= km - 1; }
                if (km) { c3 = __builtin_ctzll(km); km &= km - 1; }
                if (km) { c4 = __builtin_ctzll(km); km &= km - 1; }
                if (km) { c5 = __builtin_ctzll(km); km &= km - 1; }
                if (km) { c6 = __builtin_ctzll(km); km &= km - 1; }
                if (km) { c7 = __builtin_ctzll(km); km &= km - 1; }
                ull v0=0,v1=0,v2=0,v3=0,v4=0,v5=0,v6=0,v7=0;
                if (ld) {
                    v0 = base[(size_t)c0 << 6];
                    if (c1 >= 0) v1 = base[(size_t)c1 << 6];
                    if (c2 >= 0) v2 = base[(size_t)c2 << 6];
                    if (c3 >= 0) v3 = base[(size_t)c3 << 6];
                    if (c4 >= 0) v4 = base[(size_t)c4 << 6];
                    if (c5 >= 0) v5 = base[(size_t)c5 << 6];
                    if (c6 >= 0) v6 = base[(size_t)c6 << 6];
                    if (c7 >= 0) v7 = base[(size_t)c7 << 6];
                }
                pend |= (v0 | v1 | v2 | v3) | (v4 | v5 | v6 | v7);
            }
        }
        tw = twn;
    }
    __syncthreads();

    for (int r = lane; r < POST_NMS; r += 64) {
        float4 bx = (r < kept) ? gboxes[(size_t)b*PRE_NMS + keep_idx[r]]
                               : make_float4(0.f,0.f,0.f,0.f);
        float* o = out + (size_t)(b*POST_NMS + r)*5;
        o[0]=(float)b; o[1]=bx.x; o[2]=bx.y; o[3]=bx.z; o[4]=bx.w;
    }
}

// ---------------------------------------------------------------------------
extern "C" void kernel_launch(void* const* d_in, const int* in_sizes, int n_in,
                              void* d_out, int out_size, void* d_ws, size_t ws_size,
                              hipStream_t stream) {
    (void)n_in; (void)out_size; (void)ws_size;
    const float* scores  = (const float*)d_in[0];
    const float* deltas  = (const float*)d_in[1];
    const float* im_info = (const float*)d_in[2];
    const float* anchors = (const float*)d_in[3];
    float* out = (float*)d_out;

    const int B = in_sizes[0] / (2*NA*HH*WW);   // = 2

    // ws layout: boxes4 | gboxes | ckeys | mask | diagT | superT | mcount
    float4* boxes4 = (float4*)d_ws;
    float4* gboxes = boxes4 + (size_t)B*NPROP;
    ull*    ckeys  = (ull*)(gboxes + (size_t)B*PRE_NMS);
    ull*    mask   = ckeys + (size_t)B*SELN;
    ull*    diagT  = mask + ((size_t)B*MROWS << 6);
    ull*    superT = diagT + (size_t)B*NWORDS*64;
    int*    mcount = (int*)(superT + (size_t)B*(NWORDS-1)*64);

    decode_compact<<<B, 1024, 0, stream>>>(scores, deltas, im_info, anchors,
                                           boxes4, ckeys, mcount);
    dim3 rgrid(SELN/256, B);
    rank_scatter<<<rgrid, 256, 0, stream>>>(ckeys, mcount, boxes4, gboxes);
    dim3 mgrid(NWORDS, NWORDS, B);
    mask_kernel<<<mgrid, 64, 0, stream>>>(gboxes, mask, diagT, superT);
    scan_kernel<<<B, 64, 0, stream>>>(mask, diagT, superT, gboxes, out);
}